// Round 5
// baseline (854.340 us; speedup 1.0000x reference)
//
#include <hip/hip_runtime.h>
#include <hip/hip_bf16.h>
#include <hip/hip_fp16.h>
#include <math.h>

// ---------------------------------------------------------------------------
// ChaosSSMCore: selective diag-SSM
//   B=128, T=2048, D=256, M = B*T = 262144
//   delta = softplus(x @ Wd^T); decay = exp(-delta*exp(log_a))
//   update = delta * sigmoid(x @ Ws^T) * (x @ Wi^T)
//   states = scan(decay, update);  y = states * silu(x @ Wg^T)
//   out = y @ Wo^T
// ---------------------------------------------------------------------------

typedef __attribute__((ext_vector_type(8))) short s16x8;
typedef __attribute__((ext_vector_type(4))) float f32x4;
typedef __attribute__((ext_vector_type(4))) unsigned short u16x4;

#define D_DIM 256
#define T_DIM 2048
#define B_DIM 128
#define NCHUNK 16
#define CLEN 128                 // T / NCHUNK
#define ROWB 528                 // LDS row stride bytes (33 granules of 16B)

#define GRID_DU 1024
#define TILES_DU 8               // 8192 tiles = 4096 mtiles x 2 ntiles
#define GRID_G  1024
#define TILES_G 4                // 4096 m-tiles

__device__ __forceinline__ unsigned short f2bf(float f) {
    union { float f; unsigned int u; } v; v.f = f;
    unsigned int r = v.u + 0x7fffu + ((v.u >> 16) & 1u);   // RNE
    return (unsigned short)(r >> 16);
}
__device__ __forceinline__ float bf2f(unsigned short s) {
    union { unsigned int u; float f; } v; v.u = ((unsigned int)s) << 16;
    return v.f;
}
__device__ __forceinline__ s16x8 cvt2(float4 p0, float4 p1) {
    s16x8 a;
    a[0] = (short)f2bf(p0.x); a[1] = (short)f2bf(p0.y);
    a[2] = (short)f2bf(p0.z); a[3] = (short)f2bf(p0.w);
    a[4] = (short)f2bf(p1.x); a[5] = (short)f2bf(p1.y);
    a[6] = (short)f2bf(p1.z); a[7] = (short)f2bf(p1.w);
    return a;
}

// --------------------------- prep: cast weights ---------------------------
// Wb slabs (each 65536 bf16): 0=W_delta 1=W_select 2=W_in 3=W_gate 4=W_out
__global__ __launch_bounds__(256) void prep_kernel(
    const float* __restrict__ W_in, const float* __restrict__ W_select,
    const float* __restrict__ W_gate, const float* __restrict__ W_out,
    const float* __restrict__ W_delta, const float* __restrict__ log_a,
    unsigned short* __restrict__ Wb, float* __restrict__ ea)
{
    int i = blockIdx.x * 256 + threadIdx.x;
    if (i < 5 * 65536) {
        int s = i >> 16, j = i & 65535;
        const float* src = (s == 0) ? W_delta : (s == 1) ? W_select
                         : (s == 2) ? W_in    : (s == 3) ? W_gate : W_out;
        Wb[i] = f2bf(src[j]);
    } else if (i < 5 * 65536 + 256) {
        int j = i - 5 * 65536;
        ea[j] = expf(log_a[j]);
    }
}

// --------------------------- gemm_du: delta/select/in + elementwise -------
// Persistent-pipelined: each block processes TILES_DU tiles; the next tile's
// x rows are prefetched into registers (fp32) during the current tile's MFMA.
// Tile = 64m x 128n (ntile of 2) x 3W; 4 waves, wave = 64m x 32n (acc 96).
__global__ __launch_bounds__(256, 2) void gemm_du_kernel(
    const float* __restrict__ x, const unsigned short* __restrict__ Wb,
    const float* __restrict__ ea, __half2* __restrict__ du)
{
    __shared__ unsigned short xls[64 * (ROWB / 2)];   // 33 KB
    int tid  = threadIdx.x;
    int lane = tid & 63, wid = tid >> 6;
    int l16 = lane & 15, lk = lane >> 4;

    float4 pf[8][2];   // prefetch of one 64x256 fp32 x-tile (64 VGPR)

    // prologue: issue tile-0 loads
#pragma unroll
    for (int i = 0; i < 8; ++i) {
        int e = i * 256 + tid, r = e >> 5, g = e & 31;
        const float* xp = x + (size_t)(((int)blockIdx.x >> 1) * 64 + r) * D_DIM + g * 8;
        pf[i][0] = *(const float4*)xp;
        pf[i][1] = *(const float4*)(xp + 4);
    }

#pragma unroll 1
    for (int it = 0; it < TILES_DU; ++it) {
        int tile  = it * GRID_DU + blockIdx.x;
        int mbase = (tile >> 1) * 64;
        int ntile = tile & 1;

        // convert prefetched fp32 -> bf16 (implicit vmcnt wait on pf)
        s16x8 st[8];
#pragma unroll
        for (int i = 0; i < 8; ++i) st[i] = cvt2(pf[i][0], pf[i][1]);

        __syncthreads();           // previous tile's compute done reading xls
#pragma unroll
        for (int i = 0; i < 8; ++i) {
            int e = i * 256 + tid, r = e >> 5, g = e & 31;
            *(s16x8*)((char*)xls + r * ROWB + g * 16) = st[i];
        }
        // issue next tile's loads (in flight across the whole compute phase)
        if (it + 1 < TILES_DU) {
            int mb2 = (((it + 1) * GRID_DU + blockIdx.x) >> 1) * 64;
#pragma unroll
            for (int i = 0; i < 8; ++i) {
                int e = i * 256 + tid, r = e >> 5, g = e & 31;
                const float* xp = x + (size_t)(mb2 + r) * D_DIM + g * 8;
                pf[i][0] = *(const float4*)xp;
                pf[i][1] = *(const float4*)(xp + 4);
            }
        }
        __syncthreads();           // xls ready

        int n0 = ntile * 128 + wid * 32;
        f32x4 acc[3][4][2] = {};   // [W][mf][nf]

#pragma unroll
        for (int ks = 0; ks < 8; ++ks) {
            int kb = ks * 32 + lk * 8;
            s16x8 xf[4];
#pragma unroll
            for (int mf = 0; mf < 4; ++mf)
                xf[mf] = *(const s16x8*)((const char*)xls + (mf * 16 + l16) * ROWB
                                         + (ks * 4 + lk) * 16);
#pragma unroll
            for (int w = 0; w < 3; ++w) {
#pragma unroll
                for (int nf = 0; nf < 2; ++nf) {
                    s16x8 wfr = *(const s16x8*)(
                        Wb + ((size_t)w << 16) + (size_t)(n0 + nf * 16 + l16) * D_DIM + kb);
#pragma unroll
                    for (int mf = 0; mf < 4; ++mf)
                        acc[w][mf][nf] = __builtin_amdgcn_mfma_f32_16x16x32_bf16(
                            wfr, xf[mf], acc[w][mf][nf], 0, 0, 0);
                }
            }
        }

        // epilogue: D col = lane&15 = m; D row = n = lk*4 + j; nontemporal
        int r0 = lk * 4;
#pragma unroll
        for (int mf = 0; mf < 4; ++mf) {
            int m = mbase + mf * 16 + l16;
#pragma unroll
            for (int nf = 0; nf < 2; ++nf) {
                int n = n0 + nf * 16 + r0;
                float4 eav = *(const float4*)(ea + n);
                __half2 dv[4];
#pragma unroll
                for (int j = 0; j < 4; ++j) {
                    float ad = acc[0][mf][nf][j];
                    float as = acc[1][mf][nf][j];
                    float ai = acc[2][mf][nf][j];
                    float e = __expf(ad);
                    float delta = (ad > 15.f) ? ad : __logf(1.f + e);
                    float ean = (j == 0) ? eav.x : (j == 1) ? eav.y
                              : (j == 2) ? eav.z : eav.w;
                    float dec = __expf(-delta * ean);
                    float sel = 1.f / (1.f + __expf(-as));
                    float upd = delta * sel * ai;
                    dv[j] = __floats2half2_rn(dec, upd);
                }
                __builtin_nontemporal_store(*(f32x4*)dv,
                                            (f32x4*)(du + (size_t)m * D_DIM + n));
            }
        }
    }
}

// --------------------------- gemm_gate: gate projection + silu ------------
// Same persistent-pipelined structure; tile = 64m x 256n, wave = 64m x 64n.
__global__ __launch_bounds__(256, 2) void gemm_gate_kernel(
    const float* __restrict__ x, const unsigned short* __restrict__ Wg,
    unsigned short* __restrict__ gate)
{
    __shared__ unsigned short xls[64 * (ROWB / 2)];   // 33 KB
    int tid  = threadIdx.x;
    int lane = tid & 63, wid = tid >> 6;
    int l16 = lane & 15, lk = lane >> 4;

    float4 pf[8][2];

#pragma unroll
    for (int i = 0; i < 8; ++i) {
        int e = i * 256 + tid, r = e >> 5, g = e & 31;
        const float* xp = x + (size_t)((int)blockIdx.x * 64 + r) * D_DIM + g * 8;
        pf[i][0] = *(const float4*)xp;
        pf[i][1] = *(const float4*)(xp + 4);
    }

#pragma unroll 1
    for (int it = 0; it < TILES_G; ++it) {
        int mbase = (it * GRID_G + blockIdx.x) * 64;

        s16x8 st[8];
#pragma unroll
        for (int i = 0; i < 8; ++i) st[i] = cvt2(pf[i][0], pf[i][1]);

        __syncthreads();
#pragma unroll
        for (int i = 0; i < 8; ++i) {
            int e = i * 256 + tid, r = e >> 5, g = e & 31;
            *(s16x8*)((char*)xls + r * ROWB + g * 16) = st[i];
        }
        if (it + 1 < TILES_G) {
            int mb2 = ((it + 1) * GRID_G + blockIdx.x) * 64;
#pragma unroll
            for (int i = 0; i < 8; ++i) {
                int e = i * 256 + tid, r = e >> 5, g = e & 31;
                const float* xp = x + (size_t)(mb2 + r) * D_DIM + g * 8;
                pf[i][0] = *(const float4*)xp;
                pf[i][1] = *(const float4*)(xp + 4);
            }
        }
        __syncthreads();

        int n0 = wid * 64;
        f32x4 acc[4][4] = {};          // [mf][nf]

#pragma unroll
        for (int ks = 0; ks < 8; ++ks) {
            int kb = ks * 32 + lk * 8;
            s16x8 xf[4];
#pragma unroll
            for (int mf = 0; mf < 4; ++mf)
                xf[mf] = *(const s16x8*)((const char*)xls + (mf * 16 + l16) * ROWB
                                         + (ks * 4 + lk) * 16);
#pragma unroll
            for (int nf = 0; nf < 4; ++nf) {
                s16x8 wfr = *(const s16x8*)(
                    Wg + (size_t)(n0 + nf * 16 + l16) * D_DIM + kb);
#pragma unroll
                for (int mf = 0; mf < 4; ++mf)
                    acc[mf][nf] = __builtin_amdgcn_mfma_f32_16x16x32_bf16(
                        wfr, xf[mf], acc[mf][nf], 0, 0, 0);
            }
        }

        int r0 = lk * 4;
#pragma unroll
        for (int mf = 0; mf < 4; ++mf) {
            int m = mbase + mf * 16 + l16;
#pragma unroll
            for (int nf = 0; nf < 4; ++nf) {
                int n = n0 + nf * 16 + r0;
                u16x4 gv;
#pragma unroll
                for (int j = 0; j < 4; ++j) {
                    float ag = acc[mf][nf][j];
                    gv[j] = f2bf(ag / (1.f + __expf(-ag)));
                }
                __builtin_nontemporal_store(gv,
                    (u16x4*)(gate + (size_t)m * D_DIM + n));
            }
        }
    }
}

// --------------------------- scan pass 1: chunk summaries ------------------
__global__ __launch_bounds__(256) void scan1_kernel(
    const __half2* __restrict__ du,
    float* __restrict__ cA, float* __restrict__ cS)
{
    int b = blockIdx.x >> 4;       // 128 batches
    int c = blockIdx.x & 15;       // 16 chunks
    int d = threadIdx.x;
    size_t base = ((size_t)b * T_DIM + (size_t)c * CLEN) * D_DIM + d;
    float A = 1.f, S = 0.f;
#pragma unroll 4
    for (int t = 0; t < CLEN; ++t) {
        __half2 v = du[base + (size_t)t * D_DIM];
        float dc = __low2float(v);
        float up = __high2float(v);
        A *= dc;
        S = fmaf(dc, S, up);
    }
    int idx = (b * NCHUNK + c) * D_DIM + d;
    cA[idx] = A;
    cS[idx] = S;
}

// --------------------------- scan pass 2: chunk carries --------------------
__global__ __launch_bounds__(256) void scan2_kernel(
    const float* __restrict__ cA, const float* __restrict__ cS,
    float* __restrict__ carry)
{
    int b = blockIdx.x;
    int d = threadIdx.x;
    float s = 0.f;
    for (int c = 0; c < NCHUNK; ++c) {
        int idx = (b * NCHUNK + c) * D_DIM + d;
        carry[idx] = s;                 // state entering chunk c
        s = fmaf(cA[idx], s, cS[idx]);
    }
}

// --------------------------- fused scan3 + out-projection ------------------
// block = (b, chunk): scans 128 t-rows (full D), builds y tile in LDS (bf16,
// chunk-XOR-swizzled), then computes out[128 x 256] = y @ Wo^T with MFMA.
__global__ __launch_bounds__(256) void scan_out_kernel(
    const __half2* __restrict__ du, const unsigned short* __restrict__ gate,
    const float* __restrict__ carry, const unsigned short* __restrict__ Wo,
    float* __restrict__ out)
{
    __shared__ unsigned short yls[128 * 256];   // 64 KB
    int b = blockIdx.x >> 4;
    int c = blockIdx.x & 15;
    int tid = threadIdx.x;

    // ---- phase 1: sequential scan, y -> LDS (swizzled 16B chunks) ----
    {
        int d = tid;
        size_t base = ((size_t)b * T_DIM + (size_t)c * CLEN) * D_DIM + d;
        float s = carry[(b * NCHUNK + c) * D_DIM + d];
        int dlo = d & 7, dch = d >> 3;
#pragma unroll 4
        for (int t = 0; t < CLEN; ++t) {
            __half2 v = du[base + (size_t)t * D_DIM];
            float dc = __low2float(v);
            float up = __high2float(v);
            s = fmaf(dc, s, up);
            float g = bf2f(gate[base + (size_t)t * D_DIM]);
            int off = t * 256 + ((dch ^ (t & 7)) << 3) + dlo;
            yls[off] = f2bf(s * g);
        }
    }
    __syncthreads();

    // ---- phase 2: out-tile GEMM, A-frag = Wo rows (global), B-frag = y (LDS)
    int lane = tid & 63, wid = tid >> 6;
    int l16 = lane & 15;
    int lkc = lane >> 4;            // k-subgroup 0..3
    int m0 = (wid >> 1) * 64;
    size_t rbase = (size_t)b * T_DIM + (size_t)c * CLEN;
    int r0 = lkc * 4;

    for (int nblk = 0; nblk < 2; ++nblk) {
        int n0 = (wid & 1) * 64 + nblk * 128;
        f32x4 acc[4][4] = {};
        for (int ks = 0; ks < 8; ++ks) {
            int kb = ks * 32 + lkc * 8;
            s16x8 yf[4];
#pragma unroll
            for (int mf = 0; mf < 4; ++mf) {
                int row = m0 + mf * 16 + l16;
                int chunk = (ks * 4 + lkc) ^ (row & 7);
                yf[mf] = *(const s16x8*)&yls[row * 256 + chunk * 8];
            }
#pragma unroll
            for (int nf = 0; nf < 4; ++nf) {
                s16x8 wfr = *(const s16x8*)(Wo + (size_t)(n0 + nf * 16 + l16) * D_DIM + kb);
#pragma unroll
                for (int mf = 0; mf < 4; ++mf)
                    acc[mf][nf] = __builtin_amdgcn_mfma_f32_16x16x32_bf16(
                        wfr, yf[mf], acc[mf][nf], 0, 0, 0);
            }
        }
        // D col = lane&15 = y row; D rows = n (4 consecutive) -> float4 stores
#pragma unroll
        for (int mf = 0; mf < 4; ++mf) {
            size_t rowg = rbase + m0 + mf * 16 + l16;
#pragma unroll
            for (int nf = 0; nf < 4; ++nf) {
                int n = n0 + nf * 16 + r0;
                *(f32x4*)(out + rowg * D_DIM + n) = acc[mf][nf];
            }
        }
    }
}

// ---------------------------------------------------------------------------
extern "C" void kernel_launch(void* const* d_in, const int* in_sizes, int n_in,
                              void* d_out, int out_size, void* d_ws, size_t ws_size,
                              hipStream_t stream)
{
    const float* x        = (const float*)d_in[0];
    const float* W_in     = (const float*)d_in[1];
    const float* W_select = (const float*)d_in[2];
    const float* W_gate   = (const float*)d_in[3];
    const float* W_out    = (const float*)d_in[4];
    const float* W_delta  = (const float*)d_in[5];
    const float* log_a    = (const float*)d_in[6];
    float* out = (float*)d_out;

    char* ws = (char*)d_ws;
    const size_t MB = 1ull << 20;
    unsigned short* Wb    = (unsigned short*)(ws);               // 640 KB
    float*          ea    = (float*)(ws + 655360);               // 1 KB
    __half2*        du    = (__half2*)(ws + 1 * MB);             // 256 MB
    unsigned short* gate  = (unsigned short*)(ws + 257 * MB);    // 128 MB
    float*          cA    = (float*)(ws + 385 * MB);             // 2 MB
    float*          cS    = (float*)(ws + 387 * MB);             // 2 MB
    float*          carry = (float*)(ws + 389 * MB);             // 2 MB
    // total: 391 MB

    prep_kernel<<<1281, 256, 0, stream>>>(W_in, W_select, W_gate, W_out,
                                          W_delta, log_a, Wb, ea);
    gemm_du_kernel<<<GRID_DU, 256, 0, stream>>>(x, Wb, ea, du);
    gemm_gate_kernel<<<GRID_G, 256, 0, stream>>>(x, Wb + 3 * 65536, gate);
    scan1_kernel<<<B_DIM * NCHUNK, 256, 0, stream>>>(du, cA, cS);
    scan2_kernel<<<B_DIM, 256, 0, stream>>>(cA, cS, carry);
    scan_out_kernel<<<B_DIM * NCHUNK, 256, 0, stream>>>(du, gate, carry,
                                                        Wb + 4 * 65536, out);
}